// Round 4
// baseline (153.832 us; speedup 1.0000x reference)
//
#include <hip/hip_runtime.h>
#include <hip/hip_bf16.h>
#include <hip/hip_cooperative_groups.h>
#include <stdint.h>

namespace cg = cooperative_groups;

// SpaceLoss2, round 4: single cooperative kernel (prep -> sim+argmin -> loss)
// to eliminate inter-kernel graph-node gaps. Deterministic fallback to the
// 3-kernel path if cooperative residency isn't available.
//
//   sim = ftr @ ftr^T in fp16 MFMA (fp16 dot err sd ~0.016 vs argmin
//   1st-2nd gap ~4.3 -> argmin-safe; a flip also cannot activate the relu,
//   margin ~ -100). Lower-triangle 128x128 tiles only; masked argmin merged
//   row-wise AND col-wise via u64 atomicMin on key=(ordered-bits<<32)|col
//   (matches jnp.argmin min-value-then-min-index tie-break).

typedef _Float16 f16;
typedef _Float16 f16x4 __attribute__((ext_vector_type(4)));
typedef _Float16 f16x8 __attribute__((ext_vector_type(8)));
typedef float f32x4 __attribute__((ext_vector_type(4)));
typedef unsigned long long u64;

__device__ __forceinline__ u64 float_key(float x) {
    unsigned int u = __float_as_uint(x);
    u = (u & 0x80000000u) ? ~u : (u | 0x80000000u);
    return (u64)u;
}

__device__ __forceinline__ u64 shfl_xor_u64(u64 v, int mask) {
    unsigned int lo = (unsigned int)(v & 0xFFFFFFFFULL);
    unsigned int hi = (unsigned int)(v >> 32);
    lo = __shfl_xor(lo, mask, 64);
    hi = __shfl_xor(hi, mask, 64);
    return ((u64)hi << 32) | (u64)lo;
}

__device__ __forceinline__ void async_load16(const void* g, void* lds) {
    __builtin_amdgcn_global_load_lds(
        (__attribute__((address_space(1))) void*)(g),
        (__attribute__((address_space(3))) void*)(lds),
        16, 0, 0);
}

// ---------------- phase 1: fp32 -> fp16 convert, init best/out -------------
__device__ __forceinline__ void phase_prep(
    const float* __restrict__ x, f16* __restrict__ F,
    u64* __restrict__ best, float* __restrict__ out, int B, int D)
{
    const int nthreads = gridDim.x * blockDim.x;
    const int gid = blockIdx.x * blockDim.x + threadIdx.x;
    const int n4 = (B * D) >> 2;
    for (int i = gid; i < n4; i += nthreads) {
        float4 v = ((const float4*)x)[i];
        f16x4 h = { (f16)v.x, (f16)v.y, (f16)v.z, (f16)v.w };
        ((f16x4*)F)[i] = h;
    }
    for (int i = gid; i < B; i += nthreads) best[i] = ~0ULL;
    if (gid == 0)
        __hip_atomic_store(out, 0.0f, __ATOMIC_RELAXED, __HIP_MEMORY_SCOPE_AGENT);
}

// ---------------- phase 2: triangle sim tile + fused argmin ----------------
// 128x128 tile, BK=64, 4 waves x (4x4 frags of 16x16x32 f16 MFMA).
// LDS [128][64] f16, 16B-chunk XOR-swizzled (chunk c of row r holds
// k-chunk c^(r&7)): stride-128B ds_reads become conflict-free while staying
// contiguous for global_load_lds.
__device__ __forceinline__ void phase_sim(
    const f16* __restrict__ F, const int* __restrict__ label,
    u64* __restrict__ best, int B, int K)
{
    __shared__ __align__(16) f16 sA[128 * 64];
    __shared__ __align__(16) f16 sB[128 * 64];
    __shared__ int sLabR[128];
    __shared__ int sLabC[128];
    __shared__ u64 sRedR[2][128];
    __shared__ u64 sRedC[2][128];

    // linear block id -> (bx <= by) lower-triangle coords
    int bi = blockIdx.x;
    int by = (int)((sqrtf(8.0f * (float)bi + 1.0f) - 1.0f) * 0.5f);
    while ((by + 1) * (by + 2) / 2 <= bi) ++by;
    while (by * (by + 1) / 2 > bi) --by;
    const int bx = bi - by * (by + 1) / 2;
    const bool diag = (bx == by);

    const int row0 = by * 128;
    const int col0 = bx * 128;

    const int tid  = threadIdx.x;
    const int lane = tid & 63;
    const int w    = tid >> 6;

    if (tid < 128) sLabR[tid] = label[row0 + tid];
    else           sLabC[tid - 128] = label[col0 + (tid - 128)];

    const int srow   = w * 32 + (lane >> 3);
    const int schunk = ((lane & 7) ^ (lane >> 3)) << 3;
    const f16* gA = F + (size_t)(row0 + srow) * K + schunk;
    const f16* gB = F + (size_t)(col0 + srow) * K + schunk;
    f16* lA0 = sA + (w * 32) * 64;
    f16* lB0 = sB + (w * 32) * 64;

    f32x4 acc[4][4];
#pragma unroll
    for (int i = 0; i < 4; ++i)
#pragma unroll
        for (int j = 0; j < 4; ++j) acc[i][j] = (f32x4){0.f, 0.f, 0.f, 0.f};

    const int wr = (w >> 1) * 64;
    const int wc = (w & 1) * 64;
    const int qk = lane >> 4;
    const int ln = lane & 15;

    for (int k0 = 0; k0 < K; k0 += 64) {
        __syncthreads();
#pragma unroll
        for (int t = 0; t < 4; ++t) {
            async_load16(gA + (size_t)(t * 8) * K + k0, lA0 + t * 8 * 64);
            async_load16(gB + (size_t)(t * 8) * K + k0, lB0 + t * 8 * 64);
        }
        __syncthreads();

#pragma unroll
        for (int kk = 0; kk < 2; ++kk) {
            const int q  = kk * 4 + qk;
            const int cs = ((q ^ (ln & 7)) << 3);
            f16x8 aF[4], bF[4];
#pragma unroll
            for (int f = 0; f < 4; ++f) {
                aF[f] = __builtin_bit_cast(f16x8, *(const uint4*)&sA[(wr + f * 16 + ln) * 64 + cs]);
                bF[f] = __builtin_bit_cast(f16x8, *(const uint4*)&sB[(wc + f * 16 + ln) * 64 + cs]);
            }
#pragma unroll
            for (int i = 0; i < 4; ++i)
#pragma unroll
                for (int j = 0; j < 4; ++j)
                    acc[i][j] = __builtin_amdgcn_mfma_f32_16x16x32_f16(
                        aF[i], bF[j], acc[i][j], 0, 0, 0);
        }
    }

    // row-wise argmin -> LDS slots (C/D 16x16: col = lane&15, row = quad*4+reg)
#pragma unroll
    for (int i = 0; i < 4; ++i) {
#pragma unroll
        for (int reg = 0; reg < 4; ++reg) {
            const int lr  = wr + i * 16 + qk * 4 + reg;
            const int lab = sLabR[lr];
            u64 bl = ~0ULL;
#pragma unroll
            for (int j = 0; j < 4; ++j) {
                const int c = col0 + wc + j * 16 + ln;
                u64 key = (float_key(acc[i][j][reg]) << 32) | (unsigned int)c;
                if (c != lab && key < bl) bl = key;
            }
#pragma unroll
            for (int off = 1; off < 16; off <<= 1) {
                u64 o = shfl_xor_u64(bl, off);
                if (o < bl) bl = o;
            }
            if (ln == 0) sRedR[w & 1][lr] = bl;
        }
    }

    // col-wise argmin -> LDS slots (diag tiles: duplicate set, skip)
    if (!diag) {
#pragma unroll
        for (int j = 0; j < 4; ++j) {
            const int cl  = wc + j * 16 + ln;
            const int lab = sLabC[cl];
            u64 bl = ~0ULL;
#pragma unroll
            for (int i = 0; i < 4; ++i) {
#pragma unroll
                for (int reg = 0; reg < 4; ++reg) {
                    const int rg = row0 + wr + i * 16 + qk * 4 + reg;
                    u64 key = (float_key(acc[i][j][reg]) << 32) | (unsigned int)rg;
                    if (rg != lab && key < bl) bl = key;
                }
            }
            u64 o = shfl_xor_u64(bl, 16); if (o < bl) bl = o;
            o     = shfl_xor_u64(bl, 32); if (o < bl) bl = o;
            if (qk == 0) sRedC[w >> 1][cl] = bl;
        }
    }

    __syncthreads();
    if (tid < 128) {
        u64 a = sRedR[0][tid], b = sRedR[1][tid];
        atomicMin(&best[row0 + tid], a < b ? a : b);
    } else if (!diag) {
        const int c = tid - 128;
        u64 a = sRedC[0][c], b = sRedC[1][c];
        atomicMin(&best[col0 + c], a < b ? a : b);
    }
}

// ---------------- phase 3: loss -------------------------------------------
__device__ __forceinline__ void phase_loss(
    const float* __restrict__ ftr, const float* __restrict__ proto,
    const int* __restrict__ label, u64* __restrict__ best,
    float* __restrict__ out, int B, int D, float inv_b)
{
    const int nwaves = gridDim.x * (blockDim.x >> 6);
    const int wid0   = blockIdx.x * (blockDim.x >> 6) + (threadIdx.x >> 6);
    const int lane   = threadIdx.x & 63;

    for (int row = wid0; row < B; row += nwaves) {
        const int lab = label[row];
        const u64 bk  = __hip_atomic_load(&best[row], __ATOMIC_RELAXED,
                                          __HIP_MEMORY_SCOPE_AGENT);
        const int neg = (int)(unsigned int)(bk & 0xFFFFFFFFULL);

        float pd = 0.0f, nd = 0.0f;
        for (int d = lane * 4; d < D; d += 256) {
            float4 f = *(const float4*)(ftr   + (size_t)row * D + d);
            float4 y = *(const float4*)(proto + (size_t)lab * D + d);
            float4 n = *(const float4*)(ftr   + (size_t)neg * D + d);
            float dx = f.x - y.x, dy = f.y - y.y, dz = f.z - y.z, dw = f.w - y.w;
            pd += dx * dx + dy * dy + dz * dz + dw * dw;
            dx = f.x - n.x; dy = f.y - n.y; dz = f.z - n.z; dw = f.w - n.w;
            nd += dx * dx + dy * dy + dz * dz + dw * dw;
        }
#pragma unroll
        for (int off = 32; off >= 1; off >>= 1) {
            pd += __shfl_xor(pd, off, 64);
            nd += __shfl_xor(nd, off, 64);
        }
        if (lane == 0) {
            float l = pd - nd + 0.5f;
            if (l > 0.0f) atomicAdd(out, l * inv_b);
        }
    }
}

// ---------------- fused cooperative kernel + fallback kernels --------------
__global__ __launch_bounds__(256, 3) void fused_kernel(
    const float* __restrict__ ftr, const float* __restrict__ proto,
    const int* __restrict__ label, f16* __restrict__ F,
    u64* __restrict__ best, float* __restrict__ out,
    int B, int D, float inv_b)
{
    cg::grid_group g = cg::this_grid();
    phase_prep(ftr, F, best, out, B, D);
    g.sync();
    phase_sim(F, label, best, B, D);
    g.sync();
    phase_loss(ftr, proto, label, best, out, B, D, inv_b);
}

__global__ __launch_bounds__(256) void prep_kernel(
    const float* __restrict__ x, f16* __restrict__ F,
    u64* __restrict__ best, float* __restrict__ out, int B, int D)
{
    phase_prep(x, F, best, out, B, D);
}

__global__ __launch_bounds__(256, 3) void sim_kernel(
    const f16* __restrict__ F, const int* __restrict__ label,
    u64* __restrict__ best, int B, int K)
{
    phase_sim(F, label, best, B, K);
}

__global__ __launch_bounds__(256) void loss_kernel(
    const float* __restrict__ ftr, const float* __restrict__ proto,
    const int* __restrict__ label, u64* __restrict__ best,
    float* __restrict__ out, int B, int D, float inv_b)
{
    phase_loss(ftr, proto, label, best, out, B, D, inv_b);
}

extern "C" void kernel_launch(void* const* d_in, const int* in_sizes, int n_in,
                              void* d_out, int out_size, void* d_ws, size_t ws_size,
                              hipStream_t stream) {
    const float* ftr   = (const float*)d_in[0];
    // d_in[1] = teachor_ftr unused by the reference
    const float* proto = (const float*)d_in[2];
    const int*   label = (const int*)d_in[3];

    const int B = in_sizes[3];
    const int D = in_sizes[0] / B;      // 256

    u64* best = (u64*)d_ws;
    size_t off = ((size_t)B * 8 + 255) & ~(size_t)255;
    f16* F = (f16*)((char*)d_ws + off);
    float* out = (float*)d_out;
    float inv_b = 1.0f / (float)B;

    const int nb   = B / 128;
    const int ntri = nb * (nb + 1) / 2;

    // deterministic path choice: cooperative only if all blocks co-resident
    int blocksPerCU = 0, numCU = 0, dev = 0;
    (void)hipGetDevice(&dev);
    (void)hipDeviceGetAttribute(&numCU, hipDeviceAttributeMultiprocessorCount, dev);
    (void)hipOccupancyMaxActiveBlocksPerMultiprocessor(&blocksPerCU, fused_kernel, 256, 0);
    const bool coop = (blocksPerCU > 0 && numCU > 0 &&
                       (long long)blocksPerCU * numCU >= (long long)ntri);

    if (coop) {
        void* args[] = { (void*)&ftr, (void*)&proto, (void*)&label, (void*)&F,
                         (void*)&best, (void*)&out, (void*)&B, (void*)&D, (void*)&inv_b };
        (void)hipLaunchCooperativeKernel((void*)fused_kernel, dim3(ntri), dim3(256),
                                         args, 0, stream);
    } else {
        const int prep_threads = (B * D) >> 2;
        prep_kernel<<<(prep_threads + 255) / 256, 256, 0, stream>>>(ftr, F, best, out, B, D);
        sim_kernel<<<ntri, 256, 0, stream>>>(F, label, best, B, D);
        loss_kernel<<<(B * 64 + 255) / 256, 256, 0, stream>>>(ftr, proto, label, best, out,
                                                              B, D, inv_b);
    }
}